// Round 1
// baseline (18456.180 us; speedup 1.0000x reference)
//
#include <hip/hip_runtime.h>
#include <hip/hip_bf16.h>
#include <math.h>

#define NUME 30000
#define DIM_IN 128
#define DIM_OUT 128
#define DIM_R 64
#define DIM_T 32
#define HEADS 4
#define DHEAD 32
#define R_TOTAL 17
#define N_NODES 20000
#define N_EDGES 15000
#define DIN 160
#define NEG_SLOPE 0.2f
#define ECOLS 136  /* 17 relations * (el,er) * 4 heads packed */

// ---- float atomic-max via order-preserving unsigned key ----
__device__ __forceinline__ unsigned fkey(float f){
  unsigned u = __float_as_uint(f);
  return (u & 0x80000000u) ? ~u : (u | 0x80000000u);
}
__device__ __forceinline__ float funkey(unsigned k){
  unsigned u = (k & 0x80000000u) ? (k & 0x7FFFFFFFu) : ~k;
  return __uint_as_float(u);
}
#define MKEY_NEG_INF 0x007FFFFFu  /* fkey(-inf) */

// ---- build x = [entity_emb[nid % NUME] | cos(dt*freq + phase)] ----
__global__ __launch_bounds__(256) void k_build_x(const int* node_ids, const float* entity_emb,
                                                 const float* basis_freq, const float* phase,
                                                 const int* ts_p, float* x){
  int i = blockIdx.x * 256 + threadIdx.x;
  if (i >= N_NODES * DIN) return;
  int n = i / DIN, c = i % DIN;
  int nid = node_ids[n];
  if (c < DIM_IN){
    x[i] = entity_emb[(size_t)(nid % NUME) * DIM_IN + c];
  } else {
    int t = c - DIM_IN;
    float dt = (float)(ts_p[0] - 1 - nid / NUME);
    x[i] = cosf(dt * basis_freq[t] + phase[t]);
  }
}

// ---- wa[l][k][r*8 + side*4 + h] = sum_d w[l,r,k,h*32+d] * attn_{side}[l,r,h,d] ----
__global__ __launch_bounds__(256) void k_wa(const float* fc_w, const float* attn_l,
                                            const float* attn_r, float* wa){
  int lr = blockIdx.x;            // l*17 + r
  int l = lr / R_TOTAL, r = lr % R_TOTAL;
  const float* w  = fc_w  + (size_t)lr * DIN * DIM_OUT;
  const float* al = attn_l + (size_t)lr * HEADS * DHEAD;
  const float* ar = attn_r + (size_t)lr * HEADS * DHEAD;
  for (int i = threadIdx.x; i < DIN * HEADS; i += 256){
    int k = i / HEADS, h = i % HEADS;
    float sl = 0.f, sr = 0.f;
    for (int d = 0; d < DHEAD; ++d){
      float wv = w[(size_t)k * DIM_OUT + h * DHEAD + d];
      sl += wv * al[h * DHEAD + d];
      sr += wv * ar[h * DHEAD + d];
    }
    wa[((size_t)l * DIN + k) * ECOLS + r * 8 + h]     = sl;
    wa[((size_t)l * DIN + k) * ECOLS + r * 8 + 4 + h] = sr;
  }
}

// ---- per-layer init: h_acc = 0, mkey = key(-inf), den = 0 ----
__global__ __launch_bounds__(256) void k_layer_init(float* h_acc, unsigned* mkey, float* den){
  int i = blockIdx.x * 256 + threadIdx.x;
  if (i < N_NODES * DIM_OUT) h_acc[i] = 0.f;
  if (i < R_TOTAL * N_NODES * HEADS){ mkey[i] = MKEY_NEG_INF; den[i] = 0.f; }
}

// ---- elr = x @ wa[l]  (20000x160)@(160x136): el/er for all relations/heads ----
__global__ __launch_bounds__(256) void k_elr(const float* x, const float* wa, float* elr, int l){
  __shared__ float sX[64][33];
  __shared__ float sWA[32][ECOLS];
  int n0 = blockIdx.x * 64;
  int tid = threadIdx.x;
  int nt = tid & 31, ct = tid >> 5;       // ct 0..7 -> cols ct*17..+16
  float acc[2][17] = {};
  for (int kc = 0; kc < 5; ++kc){
    __syncthreads();
    for (int i = tid; i < 64 * 32; i += 256){
      int nn = i >> 5, kk = i & 31;
      int n = n0 + nn;
      sX[nn][kk] = (n < N_NODES) ? x[(size_t)n * DIN + kc * 32 + kk] : 0.f;
    }
    for (int i = tid; i < 32 * ECOLS; i += 256){
      int kk = i / ECOLS, c = i % ECOLS;
      sWA[kk][c] = wa[((size_t)l * DIN + kc * 32 + kk) * ECOLS + c];
    }
    __syncthreads();
    for (int kk = 0; kk < 32; ++kk){
      float x0 = sX[nt][kk], x1 = sX[nt + 32][kk];
      #pragma unroll
      for (int j = 0; j < 17; ++j){
        float wv = sWA[kk][ct * 17 + j];
        acc[0][j] += x0 * wv;
        acc[1][j] += x1 * wv;
      }
    }
  }
  #pragma unroll
  for (int q = 0; q < 2; ++q){
    int n = n0 + nt + q * 32;
    if (n < N_NODES)
      for (int j = 0; j < 17; ++j)
        elr[(size_t)n * ECOLS + ct * 17 + j] = acc[q][j];
  }
}

// ---- edge pass 1: e = leakyrelu(el[src]+er[dst]); atomicMax per (r,dst,h) ----
__global__ __launch_bounds__(256) void k_edge1(const int* edge_src, const int* edge_dst,
                                               const float* elr, float* e_edge, unsigned* mkey){
  int i = blockIdx.x * 256 + threadIdx.x;
  if (i >= R_TOTAL * N_EDGES) return;
  int r = i / N_EDGES;
  int s = edge_src[i], d = edge_dst[i];
  const float* el = &elr[(size_t)s * ECOLS + r * 8];
  const float* er = &elr[(size_t)d * ECOLS + r * 8 + 4];
  #pragma unroll
  for (int h = 0; h < 4; ++h){
    float v = el[h] + er[h];
    v = v >= 0.f ? v : NEG_SLOPE * v;
    e_edge[(size_t)i * 4 + h] = v;
    atomicMax(&mkey[((size_t)r * N_NODES + d) * 4 + h], fkey(v));
  }
}

// ---- edge pass 2: ex = exp(e - m[dst]); atomicAdd den ----
__global__ __launch_bounds__(256) void k_edge2(const int* edge_dst, const float* e_edge,
                                               const unsigned* mkey, float* ex_edge, float* den){
  int i = blockIdx.x * 256 + threadIdx.x;
  if (i >= R_TOTAL * N_EDGES) return;
  int r = i / N_EDGES;
  int d = edge_dst[i];
  #pragma unroll
  for (int h = 0; h < 4; ++h){
    float m = funkey(mkey[((size_t)r * N_NODES + d) * 4 + h]);
    float ex = expf(e_edge[(size_t)i * 4 + h] - m);
    ex_edge[(size_t)i * 4 + h] = ex;
    atomicAdd(&den[((size_t)r * N_NODES + d) * 4 + h], ex);
  }
}

// ---- fused message GEMM + scatter: per 64-edge tile of relation r:
//      C[e][c] = (x[src_e] @ w[l,r])[c];  h_acc[dst_e][c] += alpha[e][c/32]*C[e][c]
#define EB 64
__global__ __launch_bounds__(256) void k_msg(const int* edge_src, const int* edge_dst,
                                             const float* x, const float* fc_w,
                                             const float* ex_edge, const float* den,
                                             float* h_acc, int l){
  __shared__ float sX[EB][161];
  __shared__ float sW[32][128];
  __shared__ float sAl[EB][4];
  __shared__ int sSrc[EB], sDst[EB];
  int r = blockIdx.y;
  int e0 = blockIdx.x * EB;
  int tid = threadIdx.x;

  if (tid < EB){
    int e = e0 + tid;
    int s = 0, d = 0;
    if (e < N_EDGES){
      s = edge_src[(size_t)r * N_EDGES + e];
      d = edge_dst[(size_t)r * N_EDGES + e];
    }
    sSrc[tid] = s; sDst[tid] = d;
  }
  {
    int e = e0 + (tid >> 2), h = tid & 3;   // 256 threads = 64 edges * 4 heads
    float a = 0.f;
    if (e < N_EDGES){
      int d = edge_dst[(size_t)r * N_EDGES + e];
      a = ex_edge[((size_t)r * N_EDGES + e) * 4 + h] /
          fmaxf(den[((size_t)r * N_NODES + d) * 4 + h], 1e-9f);
    }
    sAl[tid >> 2][h] = a;
  }
  __syncthreads();
  for (int i = tid; i < EB * DIN; i += 256){
    int e = i / DIN, k = i % DIN;
    sX[e][k] = x[(size_t)sSrc[e] * DIN + k];
  }

  const float* w = fc_w + ((size_t)(l * R_TOTAL + r)) * DIN * DIM_OUT;
  int eg = tid >> 4;   // 0..15 -> edges eg*4..+3
  int cg = tid & 15;   // 0..15 -> cols  cg*8..+7
  float acc[4][8] = {};
  for (int kc = 0; kc < 5; ++kc){
    __syncthreads();
    for (int i = tid; i < 32 * 32; i += 256){        // 32 rows x 32 float4
      int kk = i >> 5, c4 = i & 31;
      *(float4*)&sW[kk][c4 * 4] = *(const float4*)&w[(size_t)(kc * 32 + kk) * DIM_OUT + c4 * 4];
    }
    __syncthreads();
    for (int kk = 0; kk < 32; ++kk){
      float4 w0 = *(float4*)&sW[kk][cg * 8];
      float4 w1 = *(float4*)&sW[kk][cg * 8 + 4];
      #pragma unroll
      for (int i2 = 0; i2 < 4; ++i2){
        float xv = sX[eg * 4 + i2][kc * 32 + kk];
        acc[i2][0] += xv * w0.x; acc[i2][1] += xv * w0.y;
        acc[i2][2] += xv * w0.z; acc[i2][3] += xv * w0.w;
        acc[i2][4] += xv * w1.x; acc[i2][5] += xv * w1.y;
        acc[i2][6] += xv * w1.z; acc[i2][7] += xv * w1.w;
      }
    }
  }
  #pragma unroll
  for (int i2 = 0; i2 < 4; ++i2){
    int e = eg * 4 + i2;
    if (e0 + e < N_EDGES){
      int d = sDst[e];
      float a = sAl[e][cg >> 2];   // head = (cg*8)/32, 8 cols stay in one head
      #pragma unroll
      for (int j = 0; j < 8; ++j)
        atomicAdd(&h_acc[(size_t)d * DIM_OUT + cg * 8 + j], a * acc[i2][j]);
    }
  }
}

// ---- h = relu(h_acc / 17) written back into x[:, :128] ----
__global__ __launch_bounds__(256) void k_mean(const float* h_acc, float* x){
  int i = blockIdx.x * 256 + threadIdx.x;
  if (i >= N_NODES * DIM_OUT) return;
  int n = i >> 7, c = i & 127;
  float v = h_acc[i] * (1.0f / 17.0f);
  x[(size_t)n * DIN + c] = fmaxf(v, 0.f);
}

// ---- A_cat: rows 0..1023 = [h[root[1024+b]] | obj_rel_emb[rel[b]]] (feeds sub_pred)
//             rows 1024..2047 = [h[root[b]] | sub_rel_emb[rel[b]]]   (feeds obj_pred)
__global__ __launch_bounds__(256) void k_cat(const int* root_idx, const int* rel, const float* x,
                                             const float* sub_rel_emb, const float* obj_rel_emb,
                                             float* A){
  int i = blockIdx.x * 256 + threadIdx.x;
  if (i >= 2048 * 192) return;
  int row = i / 192, k = i % 192;
  int b = row & 1023;
  bool top = row < 1024;    // sub_pred rows
  float v;
  if (k < 128){
    int node = root_idx[top ? (1024 + b) : b];
    v = x[(size_t)node * DIN + k];
  } else {
    const float* re = top ? obj_rel_emb : sub_rel_emb;
    v = re[(size_t)rel[b] * DIM_R + (k - 128)];
  }
  A[i] = v;
}

// ---- classifier GEMM: (2048x192)@(192x30000), rows<1024 use sub_cls, else obj_cls ----
__global__ __launch_bounds__(256) void k_cls(const float* A, const float* w_sub, const float* b_sub,
                                             const float* w_obj, const float* b_obj, float* out){
  __shared__ float sA[64][33];
  __shared__ float sW[32][128];
  int rb = blockIdx.y, cb = blockIdx.x;
  int row0 = rb * 64, col0 = cb * 128;
  const float* w    = (rb < 16) ? w_sub : w_obj;
  const float* bias = (rb < 16) ? b_sub : b_obj;
  int tid = threadIdx.x;
  int tr = tid >> 5, tc = tid & 31;   // 8 rows x 4 cols per thread
  float acc[8][4] = {};
  for (int kc = 0; kc < 6; ++kc){
    __syncthreads();
    for (int i = tid; i < 64 * 32; i += 256){
      int rr = i >> 5, kk = i & 31;
      sA[rr][kk] = A[(size_t)(row0 + rr) * 192 + kc * 32 + kk];
    }
    for (int i = tid; i < 32 * 32; i += 256){
      int kk = i >> 5, c4 = i & 31;
      int col = col0 + c4 * 4;
      float4 v = make_float4(0.f, 0.f, 0.f, 0.f);
      if (col < 30000) v = *(const float4*)&w[(size_t)(kc * 32 + kk) * 30000 + col];
      *(float4*)&sW[kk][c4 * 4] = v;
    }
    __syncthreads();
    for (int kk = 0; kk < 32; ++kk){
      float4 wv = *(float4*)&sW[kk][tc * 4];
      #pragma unroll
      for (int i2 = 0; i2 < 8; ++i2){
        float av = sA[tr * 8 + i2][kk];
        acc[i2][0] += av * wv.x; acc[i2][1] += av * wv.y;
        acc[i2][2] += av * wv.z; acc[i2][3] += av * wv.w;
      }
    }
  }
  int col = col0 + tc * 4;
  if (col < 30000){
    float4 bv = *(const float4*)&bias[col];
    #pragma unroll
    for (int i2 = 0; i2 < 8; ++i2){
      int row = row0 + tr * 8 + i2;
      float4 o = make_float4(acc[i2][0] + bv.x, acc[i2][1] + bv.y,
                             acc[i2][2] + bv.z, acc[i2][3] + bv.w);
      *(float4*)&out[(size_t)row * 30000 + col] = o;
    }
  }
}

extern "C" void kernel_launch(void* const* d_in, const int* in_sizes, int n_in,
                              void* d_out, int out_size, void* d_ws, size_t ws_size,
                              hipStream_t stream){
  const int*   node_ids    = (const int*)  d_in[0];
  const int*   edge_src    = (const int*)  d_in[1];
  const int*   edge_dst    = (const int*)  d_in[2];
  const int*   root_idx    = (const int*)  d_in[3];
  const int*   rel         = (const int*)  d_in[4];
  const float* entity_emb  = (const float*)d_in[5];
  const float* basis_freq  = (const float*)d_in[6];
  const float* phase       = (const float*)d_in[7];
  const float* fc_w        = (const float*)d_in[8];
  const float* attn_l      = (const float*)d_in[9];
  const float* attn_r      = (const float*)d_in[10];
  const float* sub_rel_emb = (const float*)d_in[11];
  const float* obj_rel_emb = (const float*)d_in[12];
  const float* sub_cls_w   = (const float*)d_in[13];
  const float* sub_cls_b   = (const float*)d_in[14];
  const float* obj_cls_w   = (const float*)d_in[15];
  const float* obj_cls_b   = (const float*)d_in[16];
  const int*   ts_p        = (const int*)  d_in[17];
  float* out = (float*)d_out;

  char* p = (char*)d_ws;
  auto alloc = [&](size_t bytes) -> char* {
    char* q = p; p += (bytes + 255) & ~(size_t)255; return q;
  };
  float*    x       = (float*)   alloc((size_t)N_NODES * DIN * 4);
  float*    elr     = (float*)   alloc((size_t)N_NODES * ECOLS * 4);
  unsigned* mkey    = (unsigned*)alloc((size_t)R_TOTAL * N_NODES * HEADS * 4);
  float*    den     = (float*)   alloc((size_t)R_TOTAL * N_NODES * HEADS * 4);
  float*    e_edge  = (float*)   alloc((size_t)R_TOTAL * N_EDGES * HEADS * 4);
  float*    ex_edge = (float*)   alloc((size_t)R_TOTAL * N_EDGES * HEADS * 4);
  float*    h_acc   = (float*)   alloc((size_t)N_NODES * DIM_OUT * 4);
  float*    wa      = (float*)   alloc((size_t)2 * DIN * ECOLS * 4);
  float*    A_cat   = (float*)   alloc((size_t)2048 * 192 * 4);

  k_wa<<<2 * R_TOTAL, 256, 0, stream>>>(fc_w, attn_l, attn_r, wa);
  k_build_x<<<(N_NODES * DIN + 255) / 256, 256, 0, stream>>>(node_ids, entity_emb, basis_freq,
                                                             phase, ts_p, x);
  for (int l = 0; l < 2; ++l){
    k_layer_init<<<(N_NODES * DIM_OUT + 255) / 256, 256, 0, stream>>>(h_acc, mkey, den);
    k_elr<<<(N_NODES + 63) / 64, 256, 0, stream>>>(x, wa, elr, l);
    k_edge1<<<(R_TOTAL * N_EDGES + 255) / 256, 256, 0, stream>>>(edge_src, edge_dst, elr,
                                                                 e_edge, mkey);
    k_edge2<<<(R_TOTAL * N_EDGES + 255) / 256, 256, 0, stream>>>(edge_dst, e_edge, mkey,
                                                                 ex_edge, den);
    k_msg<<<dim3((N_EDGES + EB - 1) / EB, R_TOTAL), 256, 0, stream>>>(edge_src, edge_dst, x,
                                                                      fc_w, ex_edge, den,
                                                                      h_acc, l);
    k_mean<<<(N_NODES * DIM_OUT + 255) / 256, 256, 0, stream>>>(h_acc, x);
  }
  k_cat<<<(2048 * 192 + 255) / 256, 256, 0, stream>>>(root_idx, rel, x,
                                                      sub_rel_emb, obj_rel_emb, A_cat);
  k_cls<<<dim3((30000 + 127) / 128, 32), 256, 0, stream>>>(A_cat, sub_cls_w, sub_cls_b,
                                                           obj_cls_w, obj_cls_b, out);
}